// Round 8
// baseline (227.999 us; speedup 1.0000x reference)
//
#include <hip/hip_runtime.h>

// ---------------------------------------------------------------------------
// sLSTM cell, B=8192, D=1024, H=1024.
//   pre[B,4H] = [x,h_prev] @ [Wg|Rg]^T  (K = D+H = 2048)
//   i=exp(pi+bi), f=sig(pf+bf), o=sig(po+bo), z=tanh(pz+bz)
//   c=f*c_prev+i*z ; n=f*n_prev+i ; m=max(log f + m_prev, pi) ; h=o*c/n
//   outputs (flat): h, c, C_prev(copy), n, m  -- each B*H f32
//
// Round 8: R7's deep pipeline with the L2-destroying XCD swizzle REMOVED.
//   Natural bm-fast mapping: bm = blockIdx&31, bn = blockIdx>>5. Since
//   32 % 8 == 0, hardware round-robin gives XCD = bm%8: each A panel is
//   resident in exactly ONE XCD's L2 and reused by all 16 bn blocks
//   (A traffic 32MB ideal; B ~8x multiplied but only 16MB and L3-served).
//   Pipeline (unchanged from R7, ledger verified): 256x256 tile, BK=64,
//   8 waves (2M x 4N), ring-3 A (96KB) + ring-2 B (64KB) = 160KB LDS,
//   4 phases/tile: {ds_read A-quad (+B at q0) || stage 1 half-tile} ->
//   barrier -> setprio(1) 16 MFMA setprio(0) -> [vmcnt(8) at q3] -> barrier.
//   A staged 8 phases (~4100cy) ahead, B 4-6 phases; vmcnt(8) at tile T's
//   q3 retires tile T-1's stages = tile T+1's data confirmed landed.
// Gate-interleaved W packing -> fused epilogue fully lane-local (incl C_prev).
// ---------------------------------------------------------------------------

#define B_SZ 8192
#define D_SZ 1024
#define H_SZ 1024
#define K_SZ 2048   // D + H
#define N4H  4096   // 4*H

typedef __attribute__((ext_vector_type(4))) float f32x4;
typedef _Float16 f16;
typedef __attribute__((ext_vector_type(8))) f16 f16x8;
typedef unsigned short u16;
typedef __attribute__((ext_vector_type(4))) unsigned short u16x4;

static __device__ __forceinline__ u16 f2h(float f) {
    f16 h = (f16)f;
    return __builtin_bit_cast(unsigned short, h);
}

static __device__ __forceinline__ void load_lds16(const void* g, void* l) {
    __builtin_amdgcn_global_load_lds(
        (const __attribute__((address_space(1))) void*)g,
        (__attribute__((address_space(3))) void*)l, 16, 0, 0);
}

// ---------------------------------------------------------------------------
// Merged pack kernel: A[B][K]=[x|h_prev] fp16; W gate-interleaved fp16
// (packed row r -> gate (r>>4)&3, j=(r>>6)*16+(r&15), content [Wg[j]|Rg[j]]).
// ---------------------------------------------------------------------------
__global__ void convert_AW(const float* __restrict__ x, const float* __restrict__ h,
                           const float* __restrict__ Wi, const float* __restrict__ Wf,
                           const float* __restrict__ Wo, const float* __restrict__ Wz,
                           const float* __restrict__ Ri, const float* __restrict__ Rf,
                           const float* __restrict__ Ro, const float* __restrict__ Rz,
                           u16* __restrict__ A, u16* __restrict__ Wb) {
    const size_t nvecA = (size_t)B_SZ * K_SZ / 4;
    const size_t nvecW = (size_t)N4H * K_SZ / 4;
    const size_t nvec  = nvecA + nvecW;
    const size_t stride = (size_t)gridDim.x * blockDim.x;
    for (size_t v = (size_t)blockIdx.x * blockDim.x + threadIdx.x; v < nvec; v += stride) {
        const float* src;
        u16* dst;
        if (v < nvecA) {
            size_t e = v * 4;
            size_t row = e >> 11;
            int col = (int)(e & 2047);
            src = (col < D_SZ) ? (x + row * D_SZ + col)
                               : (h + row * H_SZ + (col - D_SZ));
            dst = A + e;
        } else {
            size_t e = (v - nvecA) * 4;
            size_t r = e >> 11;
            int col = (int)(e & 2047);
            int g = (int)(r >> 4) & 3;
            int j = (int)((r >> 6) << 4) | (int)(r & 15);
            const float* Wg = (g == 0) ? Wi : (g == 1) ? Wf : (g == 2) ? Wo : Wz;
            const float* Rg = (g == 0) ? Ri : (g == 1) ? Rf : (g == 2) ? Ro : Rz;
            src = (col < D_SZ) ? (Wg + (size_t)j * D_SZ + col)
                               : (Rg + (size_t)j * H_SZ + (col - D_SZ));
            dst = Wb + e;
        }
        f32x4 val = *(const f32x4*)src;
        u16x4 o;
        o[0] = f2h(val[0]); o[1] = f2h(val[1]); o[2] = f2h(val[2]); o[3] = f2h(val[3]);
        *(u16x4*)dst = o;
    }
}

// ---------------------------------------------------------------------------
// Deep-pipelined fused GEMM + sLSTM epilogue. 512 threads, 8 waves.
// ---------------------------------------------------------------------------
__global__ __launch_bounds__(512, 1)
void gemm_fused(const u16* __restrict__ A, const u16* __restrict__ W,
                const float* __restrict__ c_prev, const float* __restrict__ C_prev,
                const float* __restrict__ n_prev, const float* __restrict__ m_prev,
                const float* __restrict__ bi, const float* __restrict__ bfv,
                const float* __restrict__ bo, const float* __restrict__ bz,
                float* __restrict__ out) {
    __shared__ u16 lA[3][256 * 64];   // 96 KB, ring-3
    __shared__ u16 lB[2][256 * 64];   // 64 KB, ring-2   (160 KB total)

    const int tid = threadIdx.x;
    const int w   = tid >> 6;
    const int l   = tid & 63;
    const int wm  = w >> 2;            // 0..1 (128 M-rows)
    const int wn  = w & 3;             // 0..3 (64 packed cols)

    // Natural bm-fast mapping (NO swizzle): XCD = blockIdx%8 = bm%8, so each
    // A panel is single-XCD-L2-resident and reused by all 16 bn blocks.
    const int bm  = blockIdx.x & 31;        // 0..31, fast
    const int bn  = blockIdx.x >> 5;        // 0..15, slow
    const int m0  = bm * 256;
    const int n0r = bn * 256;

    const int lrow8 = l >> 3;                            // 0..7
    const int laneOff = lrow8 * K_SZ + ((l & 7) ^ lrow8) * 8;  // pre-swizzled src

    const int fr = l & 15;
    const int kq = l >> 4;

    const u16* Abase = A + (size_t)m0 * K_SZ + laneOff;
    const u16* Bbase = W + (size_t)n0r * K_SZ + laneOff;

    // stage one half-tile (128 rows x 64 K = 2 issues/thread), LDS linear
    auto stA = [&](int h, int kt, int s) {
#pragma unroll
        for (int r = 0; r < 2; ++r)
            load_lds16(Abase + (size_t)(h * 128 + r * 64 + w * 8) * K_SZ + kt * 64,
                       (char*)&lA[s][0] + (h * 128 + r * 64 + w * 8) * 128);
    };
    auto stB = [&](int h, int kt, int s) {
#pragma unroll
        for (int r = 0; r < 2; ++r)
            load_lds16(Bbase + (size_t)(h * 128 + r * 64 + w * 8) * K_SZ + kt * 64,
                       (char*)&lB[s][0] + (h * 128 + r * 64 + w * 8) * 128);
    };

    f32x4 acc[8][4] = {};
    f16x8 bf[4][2];      // B frags, read at q0, live all 4 phases
    f16x8 af[2][2];      // A quad frags, per phase

    auto rdB = [&](int BS) {
#pragma unroll
        for (int ni = 0; ni < 4; ++ni)
#pragma unroll
            for (int ks = 0; ks < 2; ++ks) {
                int row = wn * 64 + ni * 16 + fr;
                int seg = (ks * 4 + kq) ^ (fr & 7);
                bf[ni][ks] = *(const f16x8*)&lB[BS][row * 64 + seg * 8];
            }
    };
    auto rdA = [&](int AS, int q) {
#pragma unroll
        for (int mi2 = 0; mi2 < 2; ++mi2)
#pragma unroll
            for (int ks = 0; ks < 2; ++ks) {
                int row = wm * 128 + (q * 2 + mi2) * 16 + fr;
                int seg = (ks * 4 + kq) ^ (fr & 7);
                af[mi2][ks] = *(const f16x8*)&lA[AS][row * 64 + seg * 8];
            }
    };
    auto mfma_q = [&](int q) {
        __builtin_amdgcn_s_setprio(1);
#pragma unroll
        for (int mi2 = 0; mi2 < 2; ++mi2)
#pragma unroll
            for (int ni = 0; ni < 4; ++ni)
#pragma unroll
                for (int ks = 0; ks < 2; ++ks)
                    acc[q * 2 + mi2][ni] = __builtin_amdgcn_mfma_f32_16x16x32_f16(
                        af[mi2][ks], bf[ni][ks], acc[q * 2 + mi2][ni], 0, 0, 0);
        __builtin_amdgcn_s_setprio(0);
    };

    // one K-tile: AS/BS compile-time slots; KT2<0 => no staging (drain tiles).
    // vmmode: 8 = steady vmcnt(8), 0 = drain vmcnt(0), -1 = none.
    auto tile4 = [&](int AS, int BS, int AST, int KT2, int vmmode) {
        // q0
        rdA(AS, 0); rdB(BS);
        if (KT2 >= 0) stA(0, KT2, AST);
        __builtin_amdgcn_s_barrier();
        mfma_q(0);
        __builtin_amdgcn_s_barrier();
        // q1
        rdA(AS, 1);
        if (KT2 >= 0) stA(1, KT2, AST);
        __builtin_amdgcn_s_barrier();
        mfma_q(1);
        __builtin_amdgcn_s_barrier();
        // q2
        rdA(AS, 2);
        if (KT2 >= 0) stB(0, KT2, BS);
        __builtin_amdgcn_s_barrier();
        mfma_q(2);
        __builtin_amdgcn_s_barrier();
        // q3
        rdA(AS, 3);
        if (KT2 >= 0) stB(1, KT2, BS);
        __builtin_amdgcn_s_barrier();
        mfma_q(3);
        if (vmmode == 8)      asm volatile("s_waitcnt vmcnt(8)" ::: "memory");
        else if (vmmode == 0) asm volatile("s_waitcnt vmcnt(0)" ::: "memory");
        __builtin_amdgcn_s_barrier();
    };

    // prologue: tiles 0,1 fully staged (16 loads); vmcnt(8) -> tile0 landed.
    stA(0, 0, 0); stA(1, 0, 0); stB(0, 0, 0); stB(1, 0, 0);
    stA(0, 1, 1); stA(1, 1, 1); stB(0, 1, 1); stB(1, 1, 1);
    asm volatile("s_waitcnt vmcnt(8)" ::: "memory");
    __builtin_amdgcn_s_barrier();

    // steady: tiles 0..29 (5 groups of 6; A slots period-3, B slots period-2)
#pragma unroll 1
    for (int g = 0; g < 5; ++g) {
        const int T0 = 6 * g;
        tile4(0, 0, 2, T0 + 2, 8);
        tile4(1, 1, 0, T0 + 3, 8);
        tile4(2, 0, 1, T0 + 4, 8);
        tile4(0, 1, 2, T0 + 5, 8);
        tile4(1, 0, 0, T0 + 6, 8);
        tile4(2, 1, 1, T0 + 7, 8);
    }
    // drain: tile 30 (a0,b0) with final vmcnt(0); tile 31 (a1,b1).
    tile4(0, 0, 0, -1, 0);
    tile4(1, 1, 0, -1, -1);

    // ---- fused sLSTM epilogue (fully lane-local, incl. C_prev copy) ------
    const size_t BH = (size_t)B_SZ * H_SZ;
    const int j = ((n0r + wn * 64) >> 6) * 16 + fr;    // 0..1023
    const float bvi = bi[j], bvf = bfv[j], bvo = bo[j], bvz = bz[j];

#pragma unroll
    for (int mi = 0; mi < 8; ++mi) {
        const int rbase = m0 + wm * 128 + mi * 16 + kq * 4;
#pragma unroll
        for (int r2 = 0; r2 < 4; ++r2) {
            const size_t idx = (size_t)(rbase + r2) * H_SZ + j;
            float pi = acc[mi][0][r2] + bvi;
            float pf = acc[mi][1][r2] + bvf;
            float po = acc[mi][2][r2] + bvo;
            float pz = acc[mi][3][r2] + bvz;
            float iv = __expf(pi);
            float fv = 1.0f / (1.0f + __expf(-pf));
            float ov = 1.0f / (1.0f + __expf(-po));
            float e2 = __expf(2.0f * pz);
            float zv = 1.0f - 2.0f / (e2 + 1.0f);     // tanh(pz)
            float cv = fv * c_prev[idx] + iv * zv;
            float nv = fv * n_prev[idx] + iv;
            float mv = fmaxf(__logf(fv) + m_prev[idx], pi);
            out[idx]          = ov * (cv / nv);       // h
            out[BH + idx]     = cv;                   // c
            out[2 * BH + idx] = C_prev[idx];          // C passthrough
            out[3 * BH + idx] = nv;                   // n
            out[4 * BH + idx] = mv;                   // m
        }
    }
}

// ---------------------------------------------------------------------------
extern "C" void kernel_launch(void* const* d_in, const int* in_sizes, int n_in,
                              void* d_out, int out_size, void* d_ws, size_t ws_size,
                              hipStream_t stream) {
    const float* x      = (const float*)d_in[0];
    const float* h_prev = (const float*)d_in[1];
    const float* c_prev = (const float*)d_in[2];
    const float* C_prev = (const float*)d_in[3];
    const float* n_prev = (const float*)d_in[4];
    const float* m_prev = (const float*)d_in[5];
    const float* Wz = (const float*)d_in[6];
    const float* bz = (const float*)d_in[7];
    const float* Rz = (const float*)d_in[8];
    const float* Wi = (const float*)d_in[9];
    const float* bi = (const float*)d_in[10];
    const float* Ri = (const float*)d_in[11];
    const float* Wf = (const float*)d_in[12];
    const float* bf = (const float*)d_in[13];
    const float* Rf = (const float*)d_in[14];
    const float* Wo = (const float*)d_in[15];
    const float* bo = (const float*)d_in[16];
    const float* Ro = (const float*)d_in[17];
    float* out = (float*)d_out;

    // workspace layout: A_f16 (32MB) | W_f16 (16MB)
    u16* Abuf = (u16*)d_ws;
    u16* Wbuf = (u16*)((char*)d_ws + (size_t)32 * 1024 * 1024);

    convert_AW<<<2048, 256, 0, stream>>>(x, h_prev, Wi, Wf, Wo, Wz,
                                         Ri, Rf, Ro, Rz, Abuf, Wbuf);

    gemm_fused<<<dim3(512), 512, 0, stream>>>(
        Abuf, Wbuf, c_prev, C_prev, n_prev, m_prev, bi, bf, bo, bz, out);
}

// Round 9
// 216.245 us; speedup vs baseline: 1.0544x; 1.0544x over previous
//
#include <hip/hip_runtime.h>

// ---------------------------------------------------------------------------
// sLSTM cell, B=8192, D=1024, H=1024.
//   pre[B,4H] = [x,h_prev] @ [Wg|Rg]^T  (K = D+H = 2048)
//   i=exp(pi+bi), f=sig(pf+bf), o=sig(po+bo), z=tanh(pz+bz)
//   c=f*c_prev+i*z ; n=f*n_prev+i ; m=max(log f + m_prev, pi) ; h=o*c/n
//   outputs (flat): h, c, C_prev(copy), n, m  -- each B*H f32
//
// Round 9: consolidation to the measured-best variant of every piece.
//   - GEMM K-loop = round-2 exactly: 128x128 tile, BK=64, 4 waves, 32KB LDS,
//     2 syncthreads/tile, NO setprio (hurts pre-8-phase GEMM), 64 VGPR ->
//     3 blocks/CU; cross-block overlap hides staging (best measured: 187us).
//   - Epilogue = round-2 lean form (inline loads, writes h/c/n/m only).
//   - C_prev passthrough folded into the MEMORY-BOUND convert kernel
//     (not the GEMM epilogue: that cost 4 VGPR -> occupancy cliff in R6).
//   - One convert launch total.
// Gate-interleaved W packing: packed row r -> gate (r>>4)&3,
// j=(r>>6)*16+(r&15) => a wave's 4 N-frags are {pi,pf,po,pz} of the same j.
// ---------------------------------------------------------------------------

#define B_SZ 8192
#define D_SZ 1024
#define H_SZ 1024
#define K_SZ 2048   // D + H
#define N4H  4096   // 4*H

typedef __attribute__((ext_vector_type(4))) float f32x4;
typedef _Float16 f16;
typedef __attribute__((ext_vector_type(8))) f16 f16x8;
typedef unsigned short u16;
typedef __attribute__((ext_vector_type(4))) unsigned short u16x4;

static __device__ __forceinline__ u16 f2h(float f) {
    f16 h = (f16)f;
    return __builtin_bit_cast(unsigned short, h);
}

static __device__ __forceinline__ void load_lds16(const void* g, void* l) {
    __builtin_amdgcn_global_load_lds(
        (const __attribute__((address_space(1))) void*)g,
        (__attribute__((address_space(3))) void*)l, 16, 0, 0);
}

// ---------------------------------------------------------------------------
// Merged pack + passthrough kernel.
//   Part 1: A[B][K] = [x | h_prev] as fp16.
//   Part 2: W[4H][K] gate-interleaved fp16 (row r -> gate (r>>4)&3,
//           j=(r>>6)*16+(r&15), content [Wg[j,:] | Rg[j,:]]).
//   Part 3: out[2*BH .. 3*BH) = C_prev  (f32x4 copy).
// ---------------------------------------------------------------------------
__global__ void convert_AW(const float* __restrict__ x, const float* __restrict__ h,
                           const float* __restrict__ Wi, const float* __restrict__ Wf,
                           const float* __restrict__ Wo, const float* __restrict__ Wz,
                           const float* __restrict__ Ri, const float* __restrict__ Rf,
                           const float* __restrict__ Ro, const float* __restrict__ Rz,
                           const float* __restrict__ C_prev,
                           u16* __restrict__ A, u16* __restrict__ Wb,
                           float* __restrict__ outC) {
    const size_t nvecA = (size_t)B_SZ * K_SZ / 4;
    const size_t nvecW = (size_t)N4H * K_SZ / 4;
    const size_t nvecC = (size_t)B_SZ * H_SZ / 4;
    const size_t nvec  = nvecA + nvecW + nvecC;
    const size_t stride = (size_t)gridDim.x * blockDim.x;
    for (size_t v = (size_t)blockIdx.x * blockDim.x + threadIdx.x; v < nvec; v += stride) {
        if (v >= nvecA + nvecW) {
            size_t e = (v - nvecA - nvecW) * 4;
            *(f32x4*)&outC[e] = *(const f32x4*)&C_prev[e];
            continue;
        }
        const float* src;
        u16* dst;
        if (v < nvecA) {
            size_t e = v * 4;
            size_t row = e >> 11;
            int col = (int)(e & 2047);
            src = (col < D_SZ) ? (x + row * D_SZ + col)
                               : (h + row * H_SZ + (col - D_SZ));
            dst = A + e;
        } else {
            size_t e = (v - nvecA) * 4;
            size_t r = e >> 11;                 // packed row 0..4095
            int col = (int)(e & 2047);
            int g = (int)(r >> 4) & 3;          // gate
            int j = (int)((r >> 6) << 4) | (int)(r & 15);
            const float* Wg = (g == 0) ? Wi : (g == 1) ? Wf : (g == 2) ? Wo : Wz;
            const float* Rg = (g == 0) ? Ri : (g == 1) ? Rf : (g == 2) ? Ro : Rz;
            src = (col < D_SZ) ? (Wg + (size_t)j * D_SZ + col)
                               : (Rg + (size_t)j * H_SZ + (col - D_SZ));
            dst = Wb + e;
        }
        f32x4 val = *(const f32x4*)src;
        u16x4 o;
        o[0] = f2h(val[0]); o[1] = f2h(val[1]); o[2] = f2h(val[2]); o[3] = f2h(val[3]);
        *(u16x4*)dst = o;
    }
}

// ---------------------------------------------------------------------------
// Fused GEMM + sLSTM epilogue (round-2 structure, verbatim K-loop).
// 256 threads, 4 waves, 128x128 tile, BK=64.
// ---------------------------------------------------------------------------
__global__ __launch_bounds__(256, 2)
void gemm_fused(const u16* __restrict__ A, const u16* __restrict__ W,
                const float* __restrict__ c_prev, const float* __restrict__ n_prev,
                const float* __restrict__ m_prev,
                const float* __restrict__ bi, const float* __restrict__ bfv,
                const float* __restrict__ bo, const float* __restrict__ bz,
                float* __restrict__ out) {
    __shared__ u16 lA[128 * 64];   // 16 KB
    __shared__ u16 lB[128 * 64];   // 16 KB

    const int tid = threadIdx.x;
    const int w  = tid >> 6;       // wave 0..3
    const int l  = tid & 63;       // lane
    const int wm = w >> 1;         // wave row (2)
    const int wn = w & 1;          // wave col (2)
    const int m0 = blockIdx.x * 128;
    const int n0 = blockIdx.y * 128;

    const int lrow8 = l >> 3;            // row within the wave's 8-row stripe
    const int lseg  = (l & 7) ^ lrow8;   // pre-swizzled global 16B-segment index

    const int fr = l & 15;   // fragment row (M for A, N for B), also C col
    const int kq = l >> 4;   // k-quad 0..3

    f32x4 acc[4][4] = {};

    for (int kt = 0; kt < K_SZ; kt += 64) {
        // ---- stage: 4 rounds x (A,B); each wave moves 1KB per call -------
#pragma unroll
        for (int r = 0; r < 4; ++r) {
            int rowA = r * 32 + w * 8 + lrow8;               // 0..127
            const u16* gA = A + (size_t)(m0 + rowA) * K_SZ + kt + lseg * 8;
            load_lds16(gA, (char*)lA + (r * 32 + w * 8) * 128);
            const u16* gB = W + (size_t)(n0 + rowA) * K_SZ + kt + lseg * 8;
            load_lds16(gB, (char*)lB + (r * 32 + w * 8) * 128);
        }
        __syncthreads();

        // ---- compute: 2 k-slices of 32, 4x4 frags ------------------------
#pragma unroll
        for (int ks = 0; ks < 2; ++ks) {
            f16x8 af[4], bfr[4];
#pragma unroll
            for (int mi = 0; mi < 4; ++mi) {
                int row = wm * 64 + mi * 16 + fr;
                int seg = (ks * 4 + kq) ^ (row & 7);
                af[mi] = *(const f16x8*)&lA[row * 64 + seg * 8];
            }
#pragma unroll
            for (int ni = 0; ni < 4; ++ni) {
                int row = wn * 64 + ni * 16 + fr;
                int seg = (ks * 4 + kq) ^ (row & 7);
                bfr[ni] = *(const f16x8*)&lB[row * 64 + seg * 8];
            }
#pragma unroll
            for (int mi = 0; mi < 4; ++mi)
#pragma unroll
                for (int ni = 0; ni < 4; ++ni)
                    acc[mi][ni] = __builtin_amdgcn_mfma_f32_16x16x32_f16(
                        af[mi], bfr[ni], acc[mi][ni], 0, 0, 0);
        }
        __syncthreads();
    }

    // ---- fused sLSTM epilogue (fully lane-local; C_prev handled in convert)
    const size_t BH = (size_t)B_SZ * H_SZ;
    const int j = ((n0 + wn * 64) >> 6) * 16 + fr;    // 0..1023
    const float bvi = bi[j], bvf = bfv[j], bvo = bo[j], bvz = bz[j];

#pragma unroll
    for (int mi = 0; mi < 4; ++mi) {
        const int rbase = m0 + wm * 64 + mi * 16 + kq * 4;
#pragma unroll
        for (int r2 = 0; r2 < 4; ++r2) {
            const size_t idx = (size_t)(rbase + r2) * H_SZ + j;
            float pi = acc[mi][0][r2] + bvi;
            float pf = acc[mi][1][r2] + bvf;
            float po = acc[mi][2][r2] + bvo;
            float pz = acc[mi][3][r2] + bvz;
            float iv = __expf(pi);
            float fv = 1.0f / (1.0f + __expf(-pf));
            float ov = 1.0f / (1.0f + __expf(-po));
            float e2 = __expf(2.0f * pz);
            float zv = 1.0f - 2.0f / (e2 + 1.0f);     // tanh(pz)
            float cv = fv * c_prev[idx] + iv * zv;
            float nv = fv * n_prev[idx] + iv;
            float mv = fmaxf(__logf(fv) + m_prev[idx], pi);
            out[idx]          = ov * (cv / nv);       // h
            out[BH + idx]     = cv;                   // c
            out[3 * BH + idx] = nv;                   // n
            out[4 * BH + idx] = mv;                   // m
        }
    }
}

// ---------------------------------------------------------------------------
extern "C" void kernel_launch(void* const* d_in, const int* in_sizes, int n_in,
                              void* d_out, int out_size, void* d_ws, size_t ws_size,
                              hipStream_t stream) {
    const float* x      = (const float*)d_in[0];
    const float* h_prev = (const float*)d_in[1];
    const float* c_prev = (const float*)d_in[2];
    const float* C_prev = (const float*)d_in[3];
    const float* n_prev = (const float*)d_in[4];
    const float* m_prev = (const float*)d_in[5];
    const float* Wz = (const float*)d_in[6];
    const float* bz = (const float*)d_in[7];
    const float* Rz = (const float*)d_in[8];
    const float* Wi = (const float*)d_in[9];
    const float* bi = (const float*)d_in[10];
    const float* Ri = (const float*)d_in[11];
    const float* Wf = (const float*)d_in[12];
    const float* bf = (const float*)d_in[13];
    const float* Rf = (const float*)d_in[14];
    const float* Wo = (const float*)d_in[15];
    const float* bo = (const float*)d_in[16];
    const float* Ro = (const float*)d_in[17];
    float* out = (float*)d_out;

    const size_t BH = (size_t)B_SZ * H_SZ;

    // workspace layout: A_f16 (32MB) | W_f16 (16MB)
    u16* Abuf = (u16*)d_ws;
    u16* Wbuf = (u16*)((char*)d_ws + (size_t)32 * 1024 * 1024);

    convert_AW<<<2048, 256, 0, stream>>>(x, h_prev, Wi, Wf, Wo, Wz,
                                         Ri, Rf, Ro, Rz, C_prev,
                                         Abuf, Wbuf, out + 2 * BH);

    gemm_fused<<<dim3(B_SZ / 128, N4H / 128), 256, 0, stream>>>(
        Abuf, Wbuf, c_prev, n_prev, m_prev, bi, bf, bo, bz, out);
}

// Round 10
// 210.445 us; speedup vs baseline: 1.0834x; 1.0276x over previous
//
#include <hip/hip_runtime.h>

// ---------------------------------------------------------------------------
// sLSTM cell, B=8192, D=1024, H=1024.
//   pre[B,4H] = [x,h_prev] @ [Wg|Rg]^T  (K = D+H = 2048)
//   i=exp(pi+bi), f=sig(pf+bf), o=sig(po+bo), z=tanh(pz+bz)
//   c=f*c_prev+i*z ; n=f*n_prev+i ; m=max(log f + m_prev, pi) ; h=o*c/n
//   outputs (flat): h, c, C_prev(copy), n, m  -- each B*H f32
//
// Round 10 = R9 + two epilogue-only changes (K-loop/grid/convert untouched):
//   1. Epilogue operands (c/n/m_prev) prefetched into LDS via per-wave
//      global_load_lds right after the final barrier (lA/lB are dead there;
//      +16KB for m -> 48KB total, still 3 blocks/CU). 12 issues fly in
//      parallel -> ONE latency exposure instead of 4 serialized per-mi
//      stalls; epilogue reads become ds_read_b32. Zero extra VGPR in-loop.
//   2. v_rcp_f32 for the 4 divides/element (2 sigmoids, tanh, c/n);
//      rel err ~1e-7, absmax margin is 0.25 vs 1.69.
// Gate-interleaved W packing: packed row r -> gate (r>>4)&3,
// j=(r>>6)*16+(r&15) => a wave's 4 N-frags are {pi,pf,po,pz} of the same j.
// ---------------------------------------------------------------------------

#define B_SZ 8192
#define D_SZ 1024
#define H_SZ 1024
#define K_SZ 2048   // D + H
#define N4H  4096   // 4*H

typedef __attribute__((ext_vector_type(4))) float f32x4;
typedef _Float16 f16;
typedef __attribute__((ext_vector_type(8))) f16 f16x8;
typedef unsigned short u16;
typedef __attribute__((ext_vector_type(4))) unsigned short u16x4;

static __device__ __forceinline__ u16 f2h(float f) {
    f16 h = (f16)f;
    return __builtin_bit_cast(unsigned short, h);
}

static __device__ __forceinline__ float rcp_fast(float x) {
    float r;
    asm("v_rcp_f32 %0, %1" : "=v"(r) : "v"(x));
    return r;
}

static __device__ __forceinline__ void load_lds16(const void* g, void* l) {
    __builtin_amdgcn_global_load_lds(
        (const __attribute__((address_space(1))) void*)g,
        (__attribute__((address_space(3))) void*)l, 16, 0, 0);
}

// ---------------------------------------------------------------------------
// Merged pack + passthrough kernel (identical to R9).
// ---------------------------------------------------------------------------
__global__ void convert_AW(const float* __restrict__ x, const float* __restrict__ h,
                           const float* __restrict__ Wi, const float* __restrict__ Wf,
                           const float* __restrict__ Wo, const float* __restrict__ Wz,
                           const float* __restrict__ Ri, const float* __restrict__ Rf,
                           const float* __restrict__ Ro, const float* __restrict__ Rz,
                           const float* __restrict__ C_prev,
                           u16* __restrict__ A, u16* __restrict__ Wb,
                           float* __restrict__ outC) {
    const size_t nvecA = (size_t)B_SZ * K_SZ / 4;
    const size_t nvecW = (size_t)N4H * K_SZ / 4;
    const size_t nvecC = (size_t)B_SZ * H_SZ / 4;
    const size_t nvec  = nvecA + nvecW + nvecC;
    const size_t stride = (size_t)gridDim.x * blockDim.x;
    for (size_t v = (size_t)blockIdx.x * blockDim.x + threadIdx.x; v < nvec; v += stride) {
        if (v >= nvecA + nvecW) {
            size_t e = (v - nvecA - nvecW) * 4;
            *(f32x4*)&outC[e] = *(const f32x4*)&C_prev[e];
            continue;
        }
        const float* src;
        u16* dst;
        if (v < nvecA) {
            size_t e = v * 4;
            size_t row = e >> 11;
            int col = (int)(e & 2047);
            src = (col < D_SZ) ? (x + row * D_SZ + col)
                               : (h + row * H_SZ + (col - D_SZ));
            dst = A + e;
        } else {
            size_t e = (v - nvecA) * 4;
            size_t r = e >> 11;                 // packed row 0..4095
            int col = (int)(e & 2047);
            int g = (int)(r >> 4) & 3;          // gate
            int j = (int)((r >> 6) << 4) | (int)(r & 15);
            const float* Wg = (g == 0) ? Wi : (g == 1) ? Wf : (g == 2) ? Wo : Wz;
            const float* Rg = (g == 0) ? Ri : (g == 1) ? Rf : (g == 2) ? Ro : Rz;
            src = (col < D_SZ) ? (Wg + (size_t)j * D_SZ + col)
                               : (Rg + (size_t)j * H_SZ + (col - D_SZ));
            dst = Wb + e;
        }
        f32x4 val = *(const f32x4*)src;
        u16x4 o;
        o[0] = f2h(val[0]); o[1] = f2h(val[1]); o[2] = f2h(val[2]); o[3] = f2h(val[3]);
        *(u16x4*)dst = o;
    }
}

// ---------------------------------------------------------------------------
// Fused GEMM + sLSTM epilogue. 256 threads, 4 waves, 128x128 tile, BK=64.
// K-loop identical to R2/R9. Epilogue operands staged to LDS.
// ---------------------------------------------------------------------------
__global__ __launch_bounds__(256, 2)
void gemm_fused(const u16* __restrict__ A, const u16* __restrict__ W,
                const float* __restrict__ c_prev, const float* __restrict__ n_prev,
                const float* __restrict__ m_prev,
                const float* __restrict__ bi, const float* __restrict__ bfv,
                const float* __restrict__ bo, const float* __restrict__ bz,
                float* __restrict__ out) {
    __shared__ char smem[49152];                 // 48KB -> 3 blocks/CU
    u16* lA = (u16*)smem;                        // 16KB (K-loop A tile)
    u16* lB = (u16*)(smem + 16384);              // 16KB (K-loop B tile)
    // epilogue overlays (valid only after final K-loop barrier):
    // per-wave [64 rows][16 cols] f32 panels, 4KB per wave per array
    float* eC = (float*)smem;                    // reuses lA space
    float* eN = (float*)(smem + 16384);          // reuses lB space
    float* eM = (float*)(smem + 32768);          // extra 16KB

    const int tid = threadIdx.x;
    const int w  = tid >> 6;       // wave 0..3
    const int l  = tid & 63;       // lane
    const int wm = w >> 1;         // wave row (2)
    const int wn = w & 1;          // wave col (2)
    const int m0 = blockIdx.x * 128;
    const int n0 = blockIdx.y * 128;

    const int lrow8 = l >> 3;            // row within the wave's 8-row stripe
    const int lseg  = (l & 7) ^ lrow8;   // pre-swizzled global 16B-segment index

    const int fr = l & 15;   // fragment row (M for A, N for B), also C col
    const int kq = l >> 4;   // k-quad 0..3

    f32x4 acc[4][4] = {};

    for (int kt = 0; kt < K_SZ; kt += 64) {
        // ---- stage: 4 rounds x (A,B); each wave moves 1KB per call -------
#pragma unroll
        for (int r = 0; r < 4; ++r) {
            int rowA = r * 32 + w * 8 + lrow8;               // 0..127
            const u16* gA = A + (size_t)(m0 + rowA) * K_SZ + kt + lseg * 8;
            load_lds16(gA, (char*)lA + (r * 32 + w * 8) * 128);
            const u16* gB = W + (size_t)(n0 + rowA) * K_SZ + kt + lseg * 8;
            load_lds16(gB, (char*)lB + (r * 32 + w * 8) * 128);
        }
        __syncthreads();

        // ---- compute: 2 k-slices of 32, 4x4 frags ------------------------
#pragma unroll
        for (int ks = 0; ks < 2; ++ks) {
            f16x8 af[4], bfr[4];
#pragma unroll
            for (int mi = 0; mi < 4; ++mi) {
                int row = wm * 64 + mi * 16 + fr;
                int seg = (ks * 4 + kq) ^ (row & 7);
                af[mi] = *(const f16x8*)&lA[row * 64 + seg * 8];
            }
#pragma unroll
            for (int ni = 0; ni < 4; ++ni) {
                int row = wn * 64 + ni * 16 + fr;
                int seg = (ks * 4 + kq) ^ (row & 7);
                bfr[ni] = *(const f16x8*)&lB[row * 64 + seg * 8];
            }
#pragma unroll
            for (int mi = 0; mi < 4; ++mi)
#pragma unroll
                for (int ni = 0; ni < 4; ++ni)
                    acc[mi][ni] = __builtin_amdgcn_mfma_f32_16x16x32_f16(
                        af[mi], bfr[ni], acc[mi][ni], 0, 0, 0);
        }
        __syncthreads();
    }
    // final __syncthreads drained vmcnt/lgkmcnt: lA/lB are dead, vmcnt == 0.

    // ---- epilogue operand prefetch into LDS (wave-local, no barrier) -----
    // wave (wm,wn) needs rows [m0+wm*64, +64) x cols [(by*2+wn)*16, +16).
    const int jbase = ((n0 + wn * 64) >> 6) * 16;      // = (by*2+wn)*16
    {
        const size_t goff = (size_t)(m0 + wm * 64) * H_SZ + jbase;
        const float* cb = c_prev + goff;
        const float* nb = n_prev + goff;
        const float* mb = m_prev + goff;
        // per issue k: lane l covers row k*16 + (l>>2), 16B chunk (l&3)
        const size_t lsrc = (size_t)(l >> 2) * H_SZ + (l & 3) * 4;
#pragma unroll
        for (int k = 0; k < 4; ++k) {
            char* ldst_c = (char*)eC + w * 4096 + k * 1024;
            char* ldst_n = (char*)eN + w * 4096 + k * 1024;
            char* ldst_m = (char*)eM + w * 4096 + k * 1024;
            load_lds16(cb + (size_t)k * 16 * H_SZ + lsrc, ldst_c);
            load_lds16(nb + (size_t)k * 16 * H_SZ + lsrc, ldst_n);
            load_lds16(mb + (size_t)k * 16 * H_SZ + lsrc, ldst_m);
        }
    }

    const size_t BH = (size_t)B_SZ * H_SZ;
    const int j = jbase + fr;                          // 0..1023
    const float bvi = bi[j], bvf = bfv[j], bvo = bo[j], bvz = bz[j];

    asm volatile("s_waitcnt vmcnt(0)" ::: "memory");   // wave's panels landed
    // lds panel layout: [64 rows][16 cols] f32 at wave base w*4096
    const int ebase = w * 1024;                        // float index

#pragma unroll
    for (int mi = 0; mi < 4; ++mi) {
        const int rbase = m0 + wm * 64 + mi * 16 + kq * 4;
        const int erow0 = mi * 16 + kq * 4;            // row within wave panel
#pragma unroll
        for (int r2 = 0; r2 < 4; ++r2) {
            const size_t idx = (size_t)(rbase + r2) * H_SZ + j;
            const int eidx = ebase + (erow0 + r2) * 16 + fr;
            float pi = acc[mi][0][r2] + bvi;
            float pf = acc[mi][1][r2] + bvf;
            float po = acc[mi][2][r2] + bvo;
            float pz = acc[mi][3][r2] + bvz;
            float iv = __expf(pi);
            float fv = rcp_fast(1.0f + __expf(-pf));           // sigmoid
            float ov = rcp_fast(1.0f + __expf(-po));           // sigmoid
            float zv = 1.0f - 2.0f * rcp_fast(__expf(2.0f * pz) + 1.0f); // tanh
            float cv = fv * eC[eidx] + iv * zv;
            float nv = fv * eN[eidx] + iv;
            float mv = fmaxf(__logf(fv) + eM[eidx], pi);
            out[idx]          = ov * cv * rcp_fast(nv);        // h
            out[BH + idx]     = cv;                            // c
            out[3 * BH + idx] = nv;                            // n
            out[4 * BH + idx] = mv;                            // m
        }
    }
}

// ---------------------------------------------------------------------------
extern "C" void kernel_launch(void* const* d_in, const int* in_sizes, int n_in,
                              void* d_out, int out_size, void* d_ws, size_t ws_size,
                              hipStream_t stream) {
    const float* x      = (const float*)d_in[0];
    const float* h_prev = (const float*)d_in[1];
    const float* c_prev = (const float*)d_in[2];
    const float* C_prev = (const float*)d_in[3];
    const float* n_prev = (const float*)d_in[4];
    const float* m_prev = (const float*)d_in[5];
    const float* Wz = (const float*)d_in[6];
    const float* bz = (const float*)d_in[7];
    const float* Rz = (const float*)d_in[8];
    const float* Wi = (const float*)d_in[9];
    const float* bi = (const float*)d_in[10];
    const float* Ri = (const float*)d_in[11];
    const float* Wf = (const float*)d_in[12];
    const float* bf = (const float*)d_in[13];
    const float* Rf = (const float*)d_in[14];
    const float* Wo = (const float*)d_in[15];
    const float* bo = (const float*)d_in[16];
    const float* Ro = (const float*)d_in[17];
    float* out = (float*)d_out;

    const size_t BH = (size_t)B_SZ * H_SZ;

    // workspace layout: A_f16 (32MB) | W_f16 (16MB)
    u16* Abuf = (u16*)d_ws;
    u16* Wbuf = (u16*)((char*)d_ws + (size_t)32 * 1024 * 1024);

    convert_AW<<<2048, 256, 0, stream>>>(x, h_prev, Wi, Wf, Wo, Wz,
                                         Ri, Rf, Ro, Rz, C_prev,
                                         Abuf, Wbuf, out + 2 * BH);

    gemm_fused<<<dim3(B_SZ / 128, N4H / 128), 256, 0, stream>>>(
        Abuf, Wbuf, c_prev, n_prev, m_prev, bi, bf, bo, bz, out);
}